// Round 4
// baseline (6335.259 us; speedup 1.0000x reference)
//
#include <hip/hip_runtime.h>
#include <hip/hip_bf16.h>
#include <hip/hip_fp16.h>

#define NNODE 16384
#define EDGES 262144
#define HOUT 64
#define TSTEPS 10
#define KT_H 1664   // 25*64 + 64 (root appended)
#define KT_X 832    // 25*32 + 32
#define NBH 8       // nodes per block, step kernel
#define NBX 16      // nodes per block, xc kernel

typedef __attribute__((ext_vector_type(8))) short bf16x8;
typedef __attribute__((ext_vector_type(4))) float f32x4;
typedef unsigned short u16;

__device__ __forceinline__ u16 f2b(float x) {
  __hip_bfloat16 b = __float2bfloat16(x);
  return *reinterpret_cast<const u16*>(&b);
}
__device__ __forceinline__ float b2f(u16 v) {
  union { unsigned u; float f; } c;
  c.u = ((unsigned)v) << 16;
  return c.f;
}

// ---------------- prep kernels ----------------

// x: (N, 32, T) f32 -> xTb: (T, N, 32) bf16
__global__ __launch_bounds__(256) void xpose_kernel(const float* __restrict__ x,
                                                    u16* __restrict__ xTb) {
  const int i = blockIdx.x * 256 + threadIdx.x;   // i = n*32 + f
  if (i >= NNODE * 32) return;
  const float* src = x + (size_t)i * TSTEPS;
  #pragma unroll
  for (int t = 0; t < TSTEPS; ++t)
    xTb[(size_t)t * NNODE * 32 + i] = f2b(src[t]);
}

__global__ __launch_bounds__(256) void deg_kernel(const int* __restrict__ ei,
                                                  int* __restrict__ degi) {
  const int e = blockIdx.x * 256 + threadIdx.x;
  if (e >= EDGES) return;
  atomicAdd(&degi[ei[EDGES + e]], 1);
}

__global__ __launch_bounds__(1024) void scan_kernel(const int* __restrict__ degi,
                                                    int* __restrict__ rp,
                                                    float* __restrict__ deg_inv) {
  __shared__ int sh[1024];
  const int tid = threadIdx.x;
  const int base = tid * 16;
  int loc[16];
  int sum = 0;
  #pragma unroll
  for (int i = 0; i < 16; ++i) { loc[i] = degi[base + i]; sum += loc[i]; }
  sh[tid] = sum;
  __syncthreads();
  for (int off = 1; off < 1024; off <<= 1) {
    int v = 0;
    if (tid >= off) v = sh[tid - off];
    __syncthreads();
    if (tid >= off) sh[tid] += v;
    __syncthreads();
  }
  int ex = sh[tid] - sum;
  #pragma unroll
  for (int i = 0; i < 16; ++i) {
    rp[base + i] = ex;
    ex += loc[i];
    deg_inv[base + i] = 1.f / (float)max(loc[i], 1);
  }
  if (tid == 1023) rp[NNODE] = ex;
}

// CSR scatter; emeta = src(14) | k0(2)<<14 | k1(2)<<16 | dst(14)<<18
__global__ __launch_bounds__(256) void scatter_kernel(const int* __restrict__ ei,
                                                      const float* __restrict__ ea,
                                                      const int* __restrict__ rp,
                                                      int* __restrict__ cursor,
                                                      int* __restrict__ emeta,
                                                      float4* __restrict__ ebasis) {
  const int e = blockIdx.x * 256 + threadIdx.x;
  if (e >= EDGES) return;
  const int s = ei[e];
  const int d = ei[EDGES + e];
  const int pos = rp[d] + atomicAdd(&cursor[d], 1);
  const float a0 = ea[2 * e], a1 = ea[2 * e + 1];
  const float f0 = a0 * 4.f, f1 = a1 * 4.f;
  const float k0f = fminf(fmaxf(floorf(f0), 0.f), 3.f);
  const float k1f = fminf(fmaxf(floorf(f1), 0.f), 3.f);
  const float t0 = f0 - k0f, t1 = f1 - k1f;
  emeta[pos] = s | ((int)k0f << 14) | ((int)k1f << 16) | (d << 18);
  float4 b;
  b.x = (1.f - t0) * (1.f - t1);   // (k0,   k1)
  b.y = (1.f - t0) * t1;           // (k0,   k1+1)
  b.z = t0 * (1.f - t1);           // (k0+1, k1)
  b.w = t0 * t1;                   // (k0+1, k1+1)
  ebasis[pos] = b;
}

// W (KSPFIN x 64) + root appended -> W_T bf16 [64][KT]
__global__ __launch_bounds__(256) void wprep_kernel(const float* __restrict__ W,
                                                    const float* __restrict__ root,
                                                    u16* __restrict__ out,
                                                    int kspfin, int kt) {
  const int i = blockIdx.x * 256 + threadIdx.x;
  if (i >= 64 * kt) return;
  const int o = i / kt, kf = i % kt;
  const float v = (kf < kspfin) ? W[(size_t)kf * 64 + o]
                                : root[(size_t)(kf - kspfin) * 64 + o];
  out[(size_t)o * kt + kf] = f2b(v);
}

// ---------------- batch x-conv kernel (all t, all 3 x-convs) ----------------

struct XP {
  const u16* xTb;
  const int* rp;
  const int* emeta;
  const float4* ebasis;
  const float* deg_inv;
  const u16* WxrT; const u16* WxzT; const u16* WxnT;
  const float* b_xr; const float* b_xz; const float* b_xn;
  __half* xcr; __half* xcz; __half* xcn;
};

__global__ __launch_bounds__(256, 2) void xc_kernel(XP p) {
  __shared__ __align__(16) float Uf[NBX * 800];    // 51200 B
  __shared__ __align__(16) u16 UXb[NBX * KT_X];    // 26624 B
  const int tid = threadIdx.x;
  const int wave = tid >> 6, lane = tid & 63;
  const int half = lane >> 5, fl = lane & 31;
  const int t = blockIdx.y;
  const int d0 = blockIdx.x * NBX;
  const u16* __restrict__ xb = p.xTb + (size_t)t * NNODE * 32;

  // zero Uf
  {
    float4* z = (float4*)Uf;
    for (int i = tid; i < NBX * 200; i += 256) z[i] = float4{0.f, 0.f, 0.f, 0.f};
  }
  __syncthreads();

  // edge phase: 8 half-wave slots, contiguous chunks, depth-2 prefetch
  {
    const int ebase = __builtin_amdgcn_readfirstlane(p.rp[d0]);
    const int eend = __builtin_amdgcn_readfirstlane(p.rp[d0 + NBX]);
    const int elen = eend - ebase;
    const int slot = wave * 2 + half;
    const int es = ebase + ((elen * slot) >> 3);
    const int ee = ebase + ((elen * (slot + 1)) >> 3);
    int m0, m1;
    float4 b0, b1;
    float v0, v1;
    {
      m0 = p.emeta[es];
      b0 = p.ebasis[es];
      const float g = b2f(xb[(size_t)(m0 & 0x3fff) * 32 + fl]);
      v0 = (es < ee) ? g : 0.f;
      m1 = p.emeta[es + 1];
      b1 = p.ebasis[es + 1];
      const float g1 = b2f(xb[(size_t)(m1 & 0x3fff) * 32 + fl]);
      v1 = (es + 1 < ee) ? g1 : 0.f;
    }
    for (int e = es; e < ee; ++e) {
      const int m2 = p.emeta[e + 2];
      const float4 b2 = p.ebasis[e + 2];
      const float g2 = b2f(xb[(size_t)(m2 & 0x3fff) * 32 + fl]);
      const float v2 = (e + 2 < ee) ? g2 : 0.f;
      const unsigned mu = (unsigned)m0;
      const int k00 = (int)((mu >> 14) & 3u) + 5 * (int)((mu >> 16) & 3u);
      const int base = (int)((mu >> 18) & 15u) * 800 + k00 * 32 + fl;
      atomicAdd(&Uf[base], b0.x * v0);        // (k0,   k1)
      atomicAdd(&Uf[base + 32], b0.z * v0);   // (k0+1, k1)
      atomicAdd(&Uf[base + 160], b0.y * v0);  // (k0,   k1+1)
      atomicAdd(&Uf[base + 192], b0.w * v0);  // (k0+1, k1+1)
      m0 = m1; b0 = b1; v0 = v1;
      m1 = m2; b1 = b2; v1 = v2;
    }
  }
  __syncthreads();

  // convert: f32 U * deg_inv -> swizzled bf16 tile; append root (raw x)
  #pragma unroll
  for (int np = 0; np < 2; ++np) {
    const int node = (tid >> 5) + np * 8;
    const float di = p.deg_inv[d0 + node];
    const int sw = (node & 7) << 3;
    u16* ux = UXb + node * KT_X;
    const float* uf = Uf + node * 800;
    for (int jj = tid & 31; jj < 800; jj += 32)
      ux[jj ^ sw] = f2b(uf[jj] * di);
  }
  for (int i = tid; i < NBX * 32; i += 256) {
    const int node = i >> 5, f = i & 31;
    UXb[node * KT_X + ((800 + f) ^ ((node & 7) << 3))] =
        xb[(size_t)(d0 + node) * 32 + f];
  }
  __syncthreads();

  // MFMA phase: wave = o-tile of 16
  const int col = lane & 15, q = lane >> 4;
  const int o = wave * 16 + col;
  const int swc = (col & 7) << 3;
  f32x4 ar, az, an;
  { const float b = p.b_xr[o]; ar = f32x4{b, b, b, b}; }
  { const float b = p.b_xz[o]; az = f32x4{b, b, b, b}; }
  { const float b = p.b_xn[o]; an = f32x4{b, b, b, b}; }
  const u16* bXr = p.WxrT + (size_t)o * KT_X + 8 * q;
  const u16* bXz = p.WxzT + (size_t)o * KT_X + 8 * q;
  const u16* bXn = p.WxnT + (size_t)o * KT_X + 8 * q;
  #pragma unroll 2
  for (int ks = 0; ks < KT_X / 32; ++ks) {
    const bf16x8 a =
        *reinterpret_cast<const bf16x8*>(UXb + col * KT_X + ((ks * 32 + q * 8) ^ swc));
    const bf16x8 wr = *reinterpret_cast<const bf16x8*>(bXr + ks * 32);
    const bf16x8 wz = *reinterpret_cast<const bf16x8*>(bXz + ks * 32);
    const bf16x8 wn = *reinterpret_cast<const bf16x8*>(bXn + ks * 32);
    ar = __builtin_amdgcn_mfma_f32_16x16x32_bf16(a, wr, ar, 0, 0, 0);
    az = __builtin_amdgcn_mfma_f32_16x16x32_bf16(a, wz, az, 0, 0, 0);
    an = __builtin_amdgcn_mfma_f32_16x16x32_bf16(a, wn, an, 0, 0, 0);
  }

  // epilogue: C layout col=lane&15, row=(lane>>4)*4+reg
  #pragma unroll
  for (int j = 0; j < 4; ++j) {
    const int r = q * 4 + j;
    const size_t ix = (size_t)t * NNODE * 64 + (size_t)(d0 + r) * 64 + o;
    p.xcr[ix] = __float2half(ar[j]);
    p.xcz[ix] = __float2half(az[j]);
    p.xcn[ix] = __float2half(an[j]);
  }
}

// ---------------- sequential step kernel (h-convs + GRU) ----------------

struct GP {
  const float* h_cur;
  const u16* h_curb;
  float* h_next;
  u16* h_nextb;
  const int* rp;
  const int* emeta;
  const float4* ebasis;
  const float* deg_inv;
  const u16* WhrT; const u16* WhzT;
  const float* b_hr; const float* b_hz;
  const __half* xcr; const __half* xcz; const __half* xcn;
  u16* hs;
};

__global__ __launch_bounds__(256, 2) void gcgru_step(GP p, int t) {
  __shared__ __align__(16) float Uf[NBH * 1600];   // 51200 B
  __shared__ __align__(16) u16 UHb[NBH * KT_H];    // 26624 B
  const int tid = threadIdx.x;
  const int wave = tid >> 6, lane = tid & 63;
  const int d0 = blockIdx.x * NBH;

  // zero Uf
  {
    float4* z = (float4*)Uf;
    for (int i = tid; i < NBH * 400; i += 256) z[i] = float4{0.f, 0.f, 0.f, 0.f};
  }
  __syncthreads();

  // edge phase: 4 wave slots, contiguous chunks, scalar meta, depth-2 prefetch
  {
    const int ebase = __builtin_amdgcn_readfirstlane(p.rp[d0]);
    const int eend = __builtin_amdgcn_readfirstlane(p.rp[d0 + NBH]);
    const int elen = eend - ebase;
    const int es = ebase + ((elen * wave) >> 2);
    const int ee = ebase + ((elen * (wave + 1)) >> 2);
    int m0, m1;
    float4 b0, b1;
    float v0, v1;
    {
      const int er0 = __builtin_amdgcn_readfirstlane(es);
      m0 = p.emeta[er0];
      b0 = p.ebasis[er0];
      const float g = b2f(p.h_curb[(size_t)(m0 & 0x3fff) * 64 + lane]);
      v0 = (es < ee) ? g : 0.f;
      const int er1 = __builtin_amdgcn_readfirstlane(es + 1);
      m1 = p.emeta[er1];
      b1 = p.ebasis[er1];
      const float g1 = b2f(p.h_curb[(size_t)(m1 & 0x3fff) * 64 + lane]);
      v1 = (es + 1 < ee) ? g1 : 0.f;
    }
    for (int e = es; e < ee; ++e) {
      const int er2 = __builtin_amdgcn_readfirstlane(e + 2);
      const int m2 = p.emeta[er2];
      const float4 b2 = p.ebasis[er2];
      const float g2 = b2f(p.h_curb[(size_t)(m2 & 0x3fff) * 64 + lane]);
      const float v2 = (e + 2 < ee) ? g2 : 0.f;
      const unsigned mu = (unsigned)m0;
      const int k00 = (int)((mu >> 14) & 3u) + 5 * (int)((mu >> 16) & 3u);
      const int base = (int)((mu >> 18) & 7u) * 1600 + k00 * 64 + lane;
      atomicAdd(&Uf[base], b0.x * v0);        // (k0,   k1)
      atomicAdd(&Uf[base + 64], b0.z * v0);   // (k0+1, k1)
      atomicAdd(&Uf[base + 320], b0.y * v0);  // (k0,   k1+1)
      atomicAdd(&Uf[base + 384], b0.w * v0);  // (k0+1, k1+1)
      m0 = m1; b0 = b1; v0 = v1;
      m1 = m2; b1 = b2; v1 = v2;
    }
  }
  __syncthreads();

  // convert: f32 U * deg_inv -> swizzled bf16 tile; append root (raw h)
  {
    const int node = tid >> 5;               // 8 nodes x 32 lanes
    const float di = p.deg_inv[d0 + node];
    const int sw = (node & 7) << 3;
    u16* uh = UHb + node * KT_H;
    const float* uf = Uf + node * 1600;
    for (int jj = tid & 31; jj < 1600; jj += 32)
      uh[jj ^ sw] = f2b(uf[jj] * di);
  }
  for (int i = tid; i < NBH * 64; i += 256) {
    const int node = i >> 6, f = i & 63;
    UHb[node * KT_H + ((1600 + f) ^ ((node & 7) << 3))] =
        p.h_curb[(size_t)(d0 + node) * 64 + f];
  }
  __syncthreads();

  // MFMA phase: A rows duplicate the 8 nodes (col&7)
  const int col = lane & 15, q = lane >> 4;
  const int o = wave * 16 + col;
  const int arow = col & 7;
  const int swc = arow << 3;
  f32x4 ahr, ahz;
  { const float b = p.b_hr[o]; ahr = f32x4{b, b, b, b}; }
  { const float b = p.b_hz[o]; ahz = f32x4{b, b, b, b}; }
  const u16* bHr = p.WhrT + (size_t)o * KT_H + 8 * q;
  const u16* bHz = p.WhzT + (size_t)o * KT_H + 8 * q;
  #pragma unroll 4
  for (int ks = 0; ks < KT_H / 32; ++ks) {
    const bf16x8 a =
        *reinterpret_cast<const bf16x8*>(UHb + arow * KT_H + ((ks * 32 + q * 8) ^ swc));
    const bf16x8 wr = *reinterpret_cast<const bf16x8*>(bHr + ks * 32);
    const bf16x8 wz = *reinterpret_cast<const bf16x8*>(bHz + ks * 32);
    ahr = __builtin_amdgcn_mfma_f32_16x16x32_bf16(a, wr, ahr, 0, 0, 0);
    ahz = __builtin_amdgcn_mfma_f32_16x16x32_bf16(a, wz, ahz, 0, 0, 0);
  }

  // GRU epilogue: rows 0..7 are the block's nodes (rows 8..15 duplicates)
  if (q < 2) {
    #pragma unroll
    for (int j = 0; j < 4; ++j) {
      const int node = d0 + q * 4 + j;
      const size_t idx = (size_t)node * 64 + o;
      const size_t tix = (size_t)t * NNODE * 64 + idx;
      const float xrv = __half2float(p.xcr[tix]);
      const float xzv = __half2float(p.xcz[tix]);
      const float xnv = __half2float(p.xcn[tix]);
      const float hrv = ahr[j], hzv = ahz[j];
      const float r = 1.f / (1.f + __expf(-(xrv + hrv)));
      const float z = 1.f / (1.f + __expf(-(xzv + hzv)));
      const float ng = 1.f - 2.f / (__expf(2.f * (xnv + r * hrv)) + 1.f);  // tanh
      const float hp = p.h_cur[idx];
      const float hn = (1.f - z) * ng + z * hp;
      p.h_next[idx] = hn;
      const u16 hb = f2b(hn);
      p.h_nextb[idx] = hb;
      p.hs[tix] = hb;
    }
  }
}

// ---------------- finalize: hs [t][n][o] bf16 -> out (B,G,H,T) f32 ----------------

__global__ __launch_bounds__(256) void finalize_kernel(const u16* __restrict__ hs,
                                                       float* __restrict__ out,
                                                       float* __restrict__ out_last) {
  const int i = blockIdx.x * 256 + threadIdx.x;   // i = n*64 + o
  if (i >= NNODE * 64) return;
  float* ob = out + (size_t)(i >> 6) * 640 + (size_t)(i & 63) * 10;
  #pragma unroll
  for (int t = 0; t < TSTEPS; ++t)
    ob[t] = b2f(hs[(size_t)t * NNODE * 64 + i]);
  out_last[i] = b2f(hs[(size_t)9 * NNODE * 64 + i]);
}

// ---------------- host launch ----------------

extern "C" void kernel_launch(void* const* d_in, const int* in_sizes, int n_in,
                              void* d_out, int out_size, void* d_ws, size_t ws_size,
                              hipStream_t stream) {
  const float* x = (const float*)d_in[0];
  const int* ei = (const int*)d_in[1];
  const float* ea = (const float*)d_in[2];
  const float* W_xr = (const float*)d_in[3];
  const float* root_xr = (const float*)d_in[4];
  const float* b_xr = (const float*)d_in[5];
  const float* W_hr = (const float*)d_in[6];
  const float* root_hr = (const float*)d_in[7];
  const float* b_hr = (const float*)d_in[8];
  const float* W_xz = (const float*)d_in[9];
  const float* root_xz = (const float*)d_in[10];
  const float* b_xz = (const float*)d_in[11];
  const float* W_hz = (const float*)d_in[12];
  const float* root_hz = (const float*)d_in[13];
  const float* b_hz = (const float*)d_in[14];
  const float* W_xn = (const float*)d_in[15];
  const float* root_xn = (const float*)d_in[16];
  const float* b_xn = (const float*)d_in[17];

  char* w = (char*)d_ws;
  u16* xTb = (u16*)w;         w += (size_t)TSTEPS * NNODE * 32 * 2;   // 10.5 MB
  __half* xcr = (__half*)w;   w += (size_t)TSTEPS * NNODE * 64 * 2;   // 21 MB
  __half* xcz = (__half*)w;   w += (size_t)TSTEPS * NNODE * 64 * 2;   // 21 MB
  __half* xcn = (__half*)w;   w += (size_t)TSTEPS * NNODE * 64 * 2;   // 21 MB
  u16* hs = (u16*)w;          w += (size_t)TSTEPS * NNODE * 64 * 2;   // 21 MB
  float* h0 = (float*)w;      w += (size_t)NNODE * HOUT * 4;
  float* h1 = (float*)w;      w += (size_t)NNODE * HOUT * 4;
  u16* h0b = (u16*)w;         w += (size_t)NNODE * HOUT * 2;
  u16* h1b = (u16*)w;         w += (size_t)NNODE * HOUT * 2;
  float4* ebasis = (float4*)w; w += (size_t)(EDGES + 16) * 16;
  int* emeta = (int*)w;       w += (size_t)(EDGES + 16) * 4;
  u16* WhrT = (u16*)w;        w += (size_t)64 * KT_H * 2;
  u16* WhzT = (u16*)w;        w += (size_t)64 * KT_H * 2;
  u16* WxrT = (u16*)w;        w += (size_t)64 * KT_X * 2;
  u16* WxzT = (u16*)w;        w += (size_t)64 * KT_X * 2;
  u16* WxnT = (u16*)w;        w += (size_t)64 * KT_X * 2;
  int* degi = (int*)w;        w += (size_t)NNODE * 4;
  int* cursor = (int*)w;      w += (size_t)NNODE * 4;
  float* deg_inv = (float*)w; w += (size_t)NNODE * 4;
  int* rp = (int*)w;          w += (size_t)(NNODE + 4) * 4;

  hipMemsetAsync(degi, 0, (size_t)NNODE * 4, stream);
  hipMemsetAsync(cursor, 0, (size_t)NNODE * 4, stream);
  hipMemsetAsync(h0, 0, (size_t)NNODE * HOUT * 4, stream);
  hipMemsetAsync(h0b, 0, (size_t)NNODE * HOUT * 2, stream);
  hipMemsetAsync(emeta + EDGES, 0, 16 * 4, stream);
  hipMemsetAsync((void*)(ebasis + EDGES), 0, 16 * 16, stream);

  xpose_kernel<<<(NNODE * 32 + 255) / 256, 256, 0, stream>>>(x, xTb);
  deg_kernel<<<(EDGES + 255) / 256, 256, 0, stream>>>(ei, degi);
  scan_kernel<<<1, 1024, 0, stream>>>(degi, rp, deg_inv);
  scatter_kernel<<<(EDGES + 255) / 256, 256, 0, stream>>>(ei, ea, rp, cursor, emeta,
                                                          ebasis);
  wprep_kernel<<<(64 * KT_H + 255) / 256, 256, 0, stream>>>(W_hr, root_hr, WhrT, 1600, KT_H);
  wprep_kernel<<<(64 * KT_H + 255) / 256, 256, 0, stream>>>(W_hz, root_hz, WhzT, 1600, KT_H);
  wprep_kernel<<<(64 * KT_X + 255) / 256, 256, 0, stream>>>(W_xr, root_xr, WxrT, 800, KT_X);
  wprep_kernel<<<(64 * KT_X + 255) / 256, 256, 0, stream>>>(W_xz, root_xz, WxzT, 800, KT_X);
  wprep_kernel<<<(64 * KT_X + 255) / 256, 256, 0, stream>>>(W_xn, root_xn, WxnT, 800, KT_X);

  XP xp;
  xp.xTb = xTb;
  xp.rp = rp;
  xp.emeta = emeta;
  xp.ebasis = ebasis;
  xp.deg_inv = deg_inv;
  xp.WxrT = WxrT; xp.WxzT = WxzT; xp.WxnT = WxnT;
  xp.b_xr = b_xr; xp.b_xz = b_xz; xp.b_xn = b_xn;
  xp.xcr = xcr; xp.xcz = xcz; xp.xcn = xcn;
  xc_kernel<<<dim3(NNODE / NBX, TSTEPS), 256, 0, stream>>>(xp);

  GP p;
  p.rp = rp;
  p.emeta = emeta;
  p.ebasis = ebasis;
  p.deg_inv = deg_inv;
  p.WhrT = WhrT; p.WhzT = WhzT;
  p.b_hr = b_hr; p.b_hz = b_hz;
  p.xcr = xcr; p.xcz = xcz; p.xcn = xcn;
  p.hs = hs;

  float* ha = h0; float* hb_ = h1;
  u16* hab = h0b; u16* hbb = h1b;
  for (int t = 0; t < TSTEPS; ++t) {
    p.h_cur = ha; p.h_curb = hab;
    p.h_next = hb_; p.h_nextb = hbb;
    gcgru_step<<<NNODE / NBH, 256, 0, stream>>>(p, t);
    float* tf = ha; ha = hb_; hb_ = tf;
    u16* tb = hab; hab = hbb; hbb = tb;
  }

  float* out = (float*)d_out;
  float* out_last = out + (size_t)NNODE * HOUT * TSTEPS;
  finalize_kernel<<<(NNODE * 64 + 255) / 256, 256, 0, stream>>>(hs, out, out_last);
}

// Round 5
// 1487.136 us; speedup vs baseline: 4.2600x; 4.2600x over previous
//
#include <hip/hip_runtime.h>
#include <hip/hip_bf16.h>
#include <hip/hip_fp16.h>

#define NNODE 16384
#define EDGES 262144
#define HOUT 64
#define TSTEPS 10
#define KT_H 1664   // 25*64 + 64 (root appended)
#define KT_X 832    // 25*32 + 32
#define NB 16       // nodes per block, step kernel
#define NBX 16      // nodes per block, xc kernel (x2 timesteps)

typedef __attribute__((ext_vector_type(8))) short bf16x8;
typedef __attribute__((ext_vector_type(4))) float f32x4;
typedef unsigned short u16;

__device__ __forceinline__ u16 f2b(float x) {
  __hip_bfloat16 b = __float2bfloat16(x);
  return *reinterpret_cast<const u16*>(&b);
}
__device__ __forceinline__ float b2f(u16 v) {
  union { unsigned u; float f; } c;
  c.u = ((unsigned)v) << 16;
  return c.f;
}

// ---------------- prep kernels ----------------

// x: (N, 32, T) f32 -> xTb: (T, N, 32) bf16
__global__ __launch_bounds__(256) void xpose_kernel(const float* __restrict__ x,
                                                    u16* __restrict__ xTb) {
  const int i = blockIdx.x * 256 + threadIdx.x;   // i = n*32 + f
  if (i >= NNODE * 32) return;
  const float* src = x + (size_t)i * TSTEPS;
  #pragma unroll
  for (int t = 0; t < TSTEPS; ++t)
    xTb[(size_t)t * NNODE * 32 + i] = f2b(src[t]);
}

__device__ __forceinline__ int cell_of(float a0, float a1, float4* b) {
  const float f0 = a0 * 4.f, f1 = a1 * 4.f;
  const float k0f = fminf(fmaxf(floorf(f0), 0.f), 3.f);
  const float k1f = fminf(fmaxf(floorf(f1), 0.f), 3.f);
  const float t0 = f0 - k0f, t1 = f1 - k1f;
  b->x = (1.f - t0) * (1.f - t1);   // (k0,   k1)
  b->y = (1.f - t0) * t1;           // (k0,   k1+1)
  b->z = t0 * (1.f - t1);           // (k0+1, k1)
  b->w = t0 * t1;                   // (k0+1, k1+1)
  return (int)k0f + 4 * (int)k1f;
}

// per-(node,cell) histogram
__global__ __launch_bounds__(256) void cellcount_kernel(const int* __restrict__ ei,
                                                        const float* __restrict__ ea,
                                                        int* __restrict__ cnt) {
  const int e = blockIdx.x * 256 + threadIdx.x;
  if (e >= EDGES) return;
  const int d = ei[EDGES + e];
  float4 b;
  const int cell = cell_of(ea[2 * e], ea[2 * e + 1], &b);
  atomicAdd(&cnt[d * 16 + cell], 1);
}

// degi[d] = sum_c cnt[d*16+c]
__global__ __launch_bounds__(256) void nodesum_kernel(const int* __restrict__ cnt,
                                                      int* __restrict__ degi) {
  const int d = blockIdx.x * 256 + threadIdx.x;
  if (d >= NNODE) return;
  int s = 0;
  #pragma unroll
  for (int c = 0; c < 16; ++c) s += cnt[d * 16 + c];
  degi[d] = s;
}

// single-block exclusive scan of 16384 degrees -> rp, deg_inv
__global__ __launch_bounds__(1024) void scan_kernel(const int* __restrict__ degi,
                                                    int* __restrict__ rp,
                                                    float* __restrict__ deg_inv) {
  __shared__ int sh[1024];
  const int tid = threadIdx.x;
  const int base = tid * 16;
  int loc[16];
  int sum = 0;
  #pragma unroll
  for (int i = 0; i < 16; ++i) { loc[i] = degi[base + i]; sum += loc[i]; }
  sh[tid] = sum;
  __syncthreads();
  for (int off = 1; off < 1024; off <<= 1) {
    int v = 0;
    if (tid >= off) v = sh[tid - off];
    __syncthreads();
    if (tid >= off) sh[tid] += v;
    __syncthreads();
  }
  int ex = sh[tid] - sum;
  #pragma unroll
  for (int i = 0; i < 16; ++i) {
    rp[base + i] = ex;
    ex += loc[i];
    deg_inv[base + i] = 1.f / (float)max(loc[i], 1);
  }
  if (tid == 1023) rp[NNODE] = ex;
}

// rp2[d*16+c] = rp[d] + prefix_c(cnt row)
__global__ __launch_bounds__(256) void rp2_kernel(const int* __restrict__ rp,
                                                  const int* __restrict__ cnt,
                                                  int* __restrict__ rp2) {
  const int d = blockIdx.x * 256 + threadIdx.x;
  if (d >= NNODE) return;
  int base = rp[d];
  #pragma unroll
  for (int c = 0; c < 16; ++c) {
    rp2[d * 16 + c] = base;
    base += cnt[d * 16 + c];
  }
  if (d == NNODE - 1) rp2[NNODE * 16] = base;
}

// scatter edges into (dst,cell)-sorted order
__global__ __launch_bounds__(256) void scatter2_kernel(const int* __restrict__ ei,
                                                       const float* __restrict__ ea,
                                                       const int* __restrict__ rp2,
                                                       int* __restrict__ cursor2,
                                                       int* __restrict__ esrc,
                                                       float4* __restrict__ ebasis) {
  const int e = blockIdx.x * 256 + threadIdx.x;
  if (e >= EDGES) return;
  const int s = ei[e];
  const int d = ei[EDGES + e];
  float4 b;
  const int cell = cell_of(ea[2 * e], ea[2 * e + 1], &b);
  const int pos = rp2[d * 16 + cell] + atomicAdd(&cursor2[d * 16 + cell], 1);
  esrc[pos] = s;
  ebasis[pos] = b;
}

// W (KSPFIN x 64) + root appended -> W_T bf16 [64][KT]
__global__ __launch_bounds__(256) void wprep_kernel(const float* __restrict__ W,
                                                    const float* __restrict__ root,
                                                    u16* __restrict__ out,
                                                    int kspfin, int kt) {
  const int i = blockIdx.x * 256 + threadIdx.x;
  if (i >= 64 * kt) return;
  const int o = i / kt, kf = i % kt;
  const float v = (kf < kspfin) ? W[(size_t)kf * 64 + o]
                                : root[(size_t)(kf - kspfin) * 64 + o];
  out[(size_t)o * kt + kf] = f2b(v);
}

// edge-phase section macro: compile-time tap slots, runtime loop (no if-convert)
#define SEC(K0, K1, BND)                                               \
  {                                                                    \
    const int eC = (BND);                                              \
    for (; e < eC; ++e) {                                              \
      const int sD = p.esrc[e + 3];                                    \
      const float4 b2 = p.ebasis[e + 2];                               \
      const float v2 = GATHER(sC);                                     \
      acc[(K0) + 5 * (K1)]     += b0.x * v0;                           \
      acc[(K0) + 5 * (K1) + 1] += b0.z * v0;                           \
      acc[(K0) + 5 * (K1) + 5] += b0.y * v0;                           \
      acc[(K0) + 5 * (K1) + 6] += b0.w * v0;                           \
      b0 = b1; b1 = b2; v0 = v1; v1 = v2; sC = sD;                     \
    }                                                                  \
  }

#define SEC_ALL                                                        \
  SEC(0, 0, q0.y) SEC(1, 0, q0.z) SEC(2, 0, q0.w) SEC(3, 0, q1.x)     \
  SEC(0, 1, q1.y) SEC(1, 1, q1.z) SEC(2, 1, q1.w) SEC(3, 1, q2.x)     \
  SEC(0, 2, q2.y) SEC(1, 2, q2.z) SEC(2, 2, q2.w) SEC(3, 2, q3.x)     \
  SEC(0, 3, q3.y) SEC(1, 3, q3.z) SEC(2, 3, q3.w) SEC(3, 3, eEnd)

// ---------------- batch x-conv kernel (t-pairs, all 3 x-convs) ----------------

struct XP {
  const u16* xTb;
  const int* rp2;
  const int* esrc;
  const float4* ebasis;
  const float* deg_inv;
  const u16* WxrT; const u16* WxzT; const u16* WxnT;
  const float* b_xr; const float* b_xz; const float* b_xn;
  __half* xcr; __half* xcz; __half* xcn;
};

__global__ __launch_bounds__(256, 4) void xc_kernel(XP p) {
  __shared__ __align__(16) u16 UXb[2 * NBX * KT_X];   // 53248 B -> 3 blocks/CU
  const int tid = threadIdx.x;
  const int wave = tid >> 6, lane = tid & 63;
  const int half = lane >> 5, fl = lane & 31;
  const int tp = blockIdx.y * 2;
  const int d0 = blockIdx.x * NBX;
  const u16* __restrict__ xb = p.xTb + (size_t)(tp + half) * NNODE * 32;

  // edge phase: wave owns 4 nodes; lanes 0-31 accumulate t, 32-63 accumulate t+1
  #pragma unroll 1
  for (int nn = 0; nn < 4; ++nn) {
    const int dloc = wave * 4 + nn;
    const int d = d0 + dloc;
    float acc[25];
    #pragma unroll
    for (int k = 0; k < 25; ++k) acc[k] = 0.f;
    const int4 q0 = *(const int4*)(p.rp2 + d * 16);
    const int4 q1 = *(const int4*)(p.rp2 + d * 16 + 4);
    const int4 q2 = *(const int4*)(p.rp2 + d * 16 + 8);
    const int4 q3 = *(const int4*)(p.rp2 + d * 16 + 12);
    const int eEnd = p.rp2[d * 16 + 16];
    int e = q0.x;
    #define GATHER(S) b2f(xb[((S) << 5) + fl])
    int sC;
    float4 b0, b1;
    float v0, v1;
    {
      const int sA = p.esrc[e], sB = p.esrc[e + 1];
      sC = p.esrc[e + 2];
      b0 = p.ebasis[e]; b1 = p.ebasis[e + 1];
      v0 = GATHER(sA); v1 = GATHER(sB);
    }
    SEC_ALL
    #undef GATHER
    const float di = p.deg_inv[d];
    const int row = dloc + half * 16;
    u16* ux = UXb + row * KT_X;
    const int sw = (row & 7) << 3;
    #pragma unroll
    for (int k = 0; k < 25; ++k) ux[(k * 32 + fl) ^ sw] = f2b(acc[k] * di);
    ux[(800 + fl) ^ sw] = xb[(d << 5) + fl];
  }
  __syncthreads();

  // MFMA: wave = o-tile of 16; rows 0-15 = t, 16-31 = t+1
  const int col = lane & 15, q = lane >> 4;
  const int o = wave * 16 + col;
  const int swc = (col & 7) << 3;
  f32x4 a0r, a0z, a0n, a1r, a1z, a1n;
  { const float b = p.b_xr[o]; a0r = f32x4{b, b, b, b}; a1r = a0r; }
  { const float b = p.b_xz[o]; a0z = f32x4{b, b, b, b}; a1z = a0z; }
  { const float b = p.b_xn[o]; a0n = f32x4{b, b, b, b}; a1n = a0n; }
  const u16* bXr = p.WxrT + (size_t)o * KT_X + 8 * q;
  const u16* bXz = p.WxzT + (size_t)o * KT_X + 8 * q;
  const u16* bXn = p.WxnT + (size_t)o * KT_X + 8 * q;
  #pragma unroll 2
  for (int ks = 0; ks < KT_X / 32; ++ks) {
    const int ofs = (ks * 32 + q * 8) ^ swc;
    const bf16x8 a0 = *reinterpret_cast<const bf16x8*>(UXb + col * KT_X + ofs);
    const bf16x8 a1 = *reinterpret_cast<const bf16x8*>(UXb + (col + 16) * KT_X + ofs);
    const bf16x8 wr = *reinterpret_cast<const bf16x8*>(bXr + ks * 32);
    const bf16x8 wz = *reinterpret_cast<const bf16x8*>(bXz + ks * 32);
    const bf16x8 wn = *reinterpret_cast<const bf16x8*>(bXn + ks * 32);
    a0r = __builtin_amdgcn_mfma_f32_16x16x32_bf16(a0, wr, a0r, 0, 0, 0);
    a0z = __builtin_amdgcn_mfma_f32_16x16x32_bf16(a0, wz, a0z, 0, 0, 0);
    a0n = __builtin_amdgcn_mfma_f32_16x16x32_bf16(a0, wn, a0n, 0, 0, 0);
    a1r = __builtin_amdgcn_mfma_f32_16x16x32_bf16(a1, wr, a1r, 0, 0, 0);
    a1z = __builtin_amdgcn_mfma_f32_16x16x32_bf16(a1, wz, a1z, 0, 0, 0);
    a1n = __builtin_amdgcn_mfma_f32_16x16x32_bf16(a1, wn, a1n, 0, 0, 0);
  }

  // epilogue: C layout col=lane&15 (node), row=(lane>>4)*4+reg
  #pragma unroll
  for (int j = 0; j < 4; ++j) {
    const int node = d0 + q * 4 + j;
    const size_t i0 = (size_t)tp * NNODE * 64 + (size_t)node * 64 + o;
    const size_t i1 = i0 + (size_t)NNODE * 64;
    p.xcr[i0] = __float2half(a0r[j]);
    p.xcz[i0] = __float2half(a0z[j]);
    p.xcn[i0] = __float2half(a0n[j]);
    p.xcr[i1] = __float2half(a1r[j]);
    p.xcz[i1] = __float2half(a1z[j]);
    p.xcn[i1] = __float2half(a1n[j]);
  }
}

// ---------------- sequential step kernel (h-convs + GRU) ----------------

struct GP {
  const float* h_cur;
  const u16* h_curb;
  float* h_next;
  u16* h_nextb;
  const int* rp2;
  const int* esrc;
  const float4* ebasis;
  const float* deg_inv;
  const u16* WhrT; const u16* WhzT;
  const float* b_hr; const float* b_hz;
  const __half* xcr; const __half* xcz; const __half* xcn;
  u16* hs;
};

__global__ __launch_bounds__(512, 4) void gcgru_step(GP p, int t) {
  __shared__ __align__(16) u16 UHb[NB * KT_H];        // 53248 B
  __shared__ float gates[2][NB][HOUT];                // 8192 B
  const int tid = threadIdx.x;
  const int wave = tid >> 6, lane = tid & 63;
  const int d0 = blockIdx.x * NB;

  // edge phase: wave owns 2 nodes; lane = feature (64)
  #pragma unroll 1
  for (int nn = 0; nn < 2; ++nn) {
    const int dloc = wave * 2 + nn;
    const int d = d0 + dloc;
    float acc[25];
    #pragma unroll
    for (int k = 0; k < 25; ++k) acc[k] = 0.f;
    const int4 q0 = *(const int4*)(p.rp2 + d * 16);
    const int4 q1 = *(const int4*)(p.rp2 + d * 16 + 4);
    const int4 q2 = *(const int4*)(p.rp2 + d * 16 + 8);
    const int4 q3 = *(const int4*)(p.rp2 + d * 16 + 12);
    const int eEnd = p.rp2[d * 16 + 16];
    int e = q0.x;
    #define GATHER(S) b2f(p.h_curb[((S) << 6) + lane])
    int sC;
    float4 b0, b1;
    float v0, v1;
    {
      const int sA = p.esrc[e], sB = p.esrc[e + 1];
      sC = p.esrc[e + 2];
      b0 = p.ebasis[e]; b1 = p.ebasis[e + 1];
      v0 = GATHER(sA); v1 = GATHER(sB);
    }
    SEC_ALL
    #undef GATHER
    const float di = p.deg_inv[d];
    u16* uh = UHb + dloc * KT_H;
    const int sw = (dloc & 7) << 3;
    #pragma unroll
    for (int k = 0; k < 25; ++k) uh[(k * 64 + lane) ^ sw] = f2b(acc[k] * di);
    uh[(1600 + lane) ^ sw] = p.h_curb[(d << 6) + lane];
  }
  __syncthreads();

  // MFMA: wave = (conv = wave&1, o-tile = wave>>1); full 16-node A tile
  const int col = lane & 15, q = lane >> 4;
  const int conv = wave & 1, ot = wave >> 1;
  const int o = ot * 16 + col;
  const int swc = (col & 7) << 3;
  const u16* WT = conv ? p.WhzT : p.WhrT;
  const float bias = conv ? p.b_hz[o] : p.b_hr[o];
  f32x4 a = f32x4{bias, bias, bias, bias};
  const u16* bW = WT + (size_t)o * KT_H + 8 * q;
  #pragma unroll 4
  for (int ks = 0; ks < KT_H / 32; ++ks) {
    const bf16x8 af =
        *reinterpret_cast<const bf16x8*>(UHb + col * KT_H + ((ks * 32 + q * 8) ^ swc));
    const bf16x8 wf = *reinterpret_cast<const bf16x8*>(bW + ks * 32);
    a = __builtin_amdgcn_mfma_f32_16x16x32_bf16(af, wf, a, 0, 0, 0);
  }
  #pragma unroll
  for (int j = 0; j < 4; ++j) gates[conv][q * 4 + j][o] = a[j];
  __syncthreads();

  // fused GRU: 1024 elems over 512 threads
  #pragma unroll
  for (int rep = 0; rep < 2; ++rep) {
    const int i = tid + rep * 512;
    const int nloc = i >> 6, oo = i & 63;
    const int node = d0 + nloc;
    const size_t idx = (size_t)node * 64 + oo;
    const size_t tix = (size_t)t * NNODE * 64 + idx;
    const float hrv = gates[0][nloc][oo];
    const float hzv = gates[1][nloc][oo];
    const float xrv = __half2float(p.xcr[tix]);
    const float xzv = __half2float(p.xcz[tix]);
    const float xnv = __half2float(p.xcn[tix]);
    const float r = 1.f / (1.f + __expf(-(xrv + hrv)));
    const float z = 1.f / (1.f + __expf(-(xzv + hzv)));
    const float ng = 1.f - 2.f / (__expf(2.f * (xnv + r * hrv)) + 1.f);  // tanh
    const float hp = p.h_cur[idx];
    const float hn = (1.f - z) * ng + z * hp;
    p.h_next[idx] = hn;
    const u16 hb = f2b(hn);
    p.h_nextb[idx] = hb;
    p.hs[tix] = hb;
  }
}

// ---------------- finalize: hs [t][n][o] bf16 -> out (B,G,H,T) f32 ----------------

__global__ __launch_bounds__(256) void finalize_kernel(const u16* __restrict__ hs,
                                                       float* __restrict__ out,
                                                       float* __restrict__ out_last) {
  const int i = blockIdx.x * 256 + threadIdx.x;   // i = n*64 + o
  if (i >= NNODE * 64) return;
  float* ob = out + (size_t)(i >> 6) * 640 + (size_t)(i & 63) * 10;
  #pragma unroll
  for (int t = 0; t < TSTEPS; ++t)
    ob[t] = b2f(hs[(size_t)t * NNODE * 64 + i]);
  out_last[i] = b2f(hs[(size_t)9 * NNODE * 64 + i]);
}

// ---------------- host launch ----------------

extern "C" void kernel_launch(void* const* d_in, const int* in_sizes, int n_in,
                              void* d_out, int out_size, void* d_ws, size_t ws_size,
                              hipStream_t stream) {
  const float* x = (const float*)d_in[0];
  const int* ei = (const int*)d_in[1];
  const float* ea = (const float*)d_in[2];
  const float* W_xr = (const float*)d_in[3];
  const float* root_xr = (const float*)d_in[4];
  const float* b_xr = (const float*)d_in[5];
  const float* W_hr = (const float*)d_in[6];
  const float* root_hr = (const float*)d_in[7];
  const float* b_hr = (const float*)d_in[8];
  const float* W_xz = (const float*)d_in[9];
  const float* root_xz = (const float*)d_in[10];
  const float* b_xz = (const float*)d_in[11];
  const float* W_hz = (const float*)d_in[12];
  const float* root_hz = (const float*)d_in[13];
  const float* b_hz = (const float*)d_in[14];
  const float* W_xn = (const float*)d_in[15];
  const float* root_xn = (const float*)d_in[16];
  const float* b_xn = (const float*)d_in[17];

  char* w = (char*)d_ws;
  u16* xTb = (u16*)w;          w += (size_t)TSTEPS * NNODE * 32 * 2;   // 10.5 MB
  __half* xcr = (__half*)w;    w += (size_t)TSTEPS * NNODE * 64 * 2;   // 21 MB
  __half* xcz = (__half*)w;    w += (size_t)TSTEPS * NNODE * 64 * 2;   // 21 MB
  __half* xcn = (__half*)w;    w += (size_t)TSTEPS * NNODE * 64 * 2;   // 21 MB
  u16* hs = (u16*)w;           w += (size_t)TSTEPS * NNODE * 64 * 2;   // 21 MB
  float* h0 = (float*)w;       w += (size_t)NNODE * HOUT * 4;
  float* h1 = (float*)w;       w += (size_t)NNODE * HOUT * 4;
  u16* h0b = (u16*)w;          w += (size_t)NNODE * HOUT * 2;
  u16* h1b = (u16*)w;          w += (size_t)NNODE * HOUT * 2;
  float4* ebasis = (float4*)w; w += (size_t)(EDGES + 16) * 16;
  int* esrc = (int*)w;         w += (size_t)(EDGES + 16) * 4;
  u16* WhrT = (u16*)w;         w += (size_t)64 * KT_H * 2;
  u16* WhzT = (u16*)w;         w += (size_t)64 * KT_H * 2;
  u16* WxrT = (u16*)w;         w += (size_t)64 * KT_X * 2;
  u16* WxzT = (u16*)w;         w += (size_t)64 * KT_X * 2;
  u16* WxnT = (u16*)w;         w += (size_t)64 * KT_X * 2;
  int* cnt = (int*)w;          w += (size_t)NNODE * 16 * 4;            // 1 MB
  int* cursor2 = (int*)w;      w += (size_t)NNODE * 16 * 4;            // 1 MB
  int* rp2 = (int*)w;          w += (size_t)(NNODE * 16 + 16) * 4;     // 1 MB
  int* degi = (int*)w;         w += (size_t)NNODE * 4;
  int* rp = (int*)w;           w += (size_t)(NNODE + 4) * 4;
  float* deg_inv = (float*)w;  w += (size_t)NNODE * 4;

  hipMemsetAsync(cnt, 0, (size_t)NNODE * 16 * 4, stream);
  hipMemsetAsync(cursor2, 0, (size_t)NNODE * 16 * 4, stream);
  hipMemsetAsync(h0, 0, (size_t)NNODE * HOUT * 4, stream);
  hipMemsetAsync(h0b, 0, (size_t)NNODE * HOUT * 2, stream);
  hipMemsetAsync((void*)(ebasis + EDGES), 0, 16 * 16, stream);
  hipMemsetAsync(esrc + EDGES, 0, 16 * 4, stream);

  xpose_kernel<<<(NNODE * 32 + 255) / 256, 256, 0, stream>>>(x, xTb);
  cellcount_kernel<<<(EDGES + 255) / 256, 256, 0, stream>>>(ei, ea, cnt);
  nodesum_kernel<<<(NNODE + 255) / 256, 256, 0, stream>>>(cnt, degi);
  scan_kernel<<<1, 1024, 0, stream>>>(degi, rp, deg_inv);
  rp2_kernel<<<(NNODE + 255) / 256, 256, 0, stream>>>(rp, cnt, rp2);
  scatter2_kernel<<<(EDGES + 255) / 256, 256, 0, stream>>>(ei, ea, rp2, cursor2,
                                                           esrc, ebasis);
  wprep_kernel<<<(64 * KT_H + 255) / 256, 256, 0, stream>>>(W_hr, root_hr, WhrT, 1600, KT_H);
  wprep_kernel<<<(64 * KT_H + 255) / 256, 256, 0, stream>>>(W_hz, root_hz, WhzT, 1600, KT_H);
  wprep_kernel<<<(64 * KT_X + 255) / 256, 256, 0, stream>>>(W_xr, root_xr, WxrT, 800, KT_X);
  wprep_kernel<<<(64 * KT_X + 255) / 256, 256, 0, stream>>>(W_xz, root_xz, WxzT, 800, KT_X);
  wprep_kernel<<<(64 * KT_X + 255) / 256, 256, 0, stream>>>(W_xn, root_xn, WxnT, 800, KT_X);

  XP xp;
  xp.xTb = xTb;
  xp.rp2 = rp2;
  xp.esrc = esrc;
  xp.ebasis = ebasis;
  xp.deg_inv = deg_inv;
  xp.WxrT = WxrT; xp.WxzT = WxzT; xp.WxnT = WxnT;
  xp.b_xr = b_xr; xp.b_xz = b_xz; xp.b_xn = b_xn;
  xp.xcr = xcr; xp.xcz = xcz; xp.xcn = xcn;
  xc_kernel<<<dim3(NNODE / NBX, TSTEPS / 2), 256, 0, stream>>>(xp);

  GP p;
  p.rp2 = rp2;
  p.esrc = esrc;
  p.ebasis = ebasis;
  p.deg_inv = deg_inv;
  p.WhrT = WhrT; p.WhzT = WhzT;
  p.b_hr = b_hr; p.b_hz = b_hz;
  p.xcr = xcr; p.xcz = xcz; p.xcn = xcn;
  p.hs = hs;

  float* ha = h0; float* hb_ = h1;
  u16* hab = h0b; u16* hbb = h1b;
  for (int t = 0; t < TSTEPS; ++t) {
    p.h_cur = ha; p.h_curb = hab;
    p.h_next = hb_; p.h_nextb = hbb;
    gcgru_step<<<NNODE / NB, 512, 0, stream>>>(p, t);
    float* tf = ha; ha = hb_; hb_ = tf;
    u16* tb = hab; hab = hbb; hbb = tb;
  }

  float* out = (float*)d_out;
  float* out_last = out + (size_t)NNODE * HOUT * TSTEPS;
  finalize_kernel<<<(NNODE * 64 + 255) / 256, 256, 0, stream>>>(hs, out, out_last);
}

// Round 6
// 1297.553 us; speedup vs baseline: 4.8825x; 1.1461x over previous
//
#include <hip/hip_runtime.h>
#include <hip/hip_bf16.h>
#include <hip/hip_fp16.h>

#define NNODE 16384
#define EDGES 262144
#define HOUT 64
#define TSTEPS 10
#define NKT_H 52    // (25*64 + 64)/32 k-tiles for h-convs
#define NKT_X 26    // (25*32 + 32)/32 k-tiles for x-convs

typedef __attribute__((ext_vector_type(8))) short bf16x8;
typedef __attribute__((ext_vector_type(4))) float f32x4;
typedef unsigned short u16;

__device__ __forceinline__ u16 f2b(float x) {
  __hip_bfloat16 b = __float2bfloat16(x);
  return *reinterpret_cast<const u16*>(&b);
}
__device__ __forceinline__ float b2f(u16 v) {
  union { unsigned u; float f; } c;
  c.u = ((unsigned)v) << 16;
  return c.f;
}

// ---------------- prep kernels ----------------

// x: (N, 32, T) f32 -> xTb: (T, N, 32) bf16
__global__ __launch_bounds__(256) void xpose_kernel(const float* __restrict__ x,
                                                    u16* __restrict__ xTb) {
  const int i = blockIdx.x * 256 + threadIdx.x;   // i = n*32 + f
  if (i >= NNODE * 32) return;
  const float* src = x + (size_t)i * TSTEPS;
  #pragma unroll
  for (int t = 0; t < TSTEPS; ++t)
    xTb[(size_t)t * NNODE * 32 + i] = f2b(src[t]);
}

__device__ __forceinline__ int cell_of(float a0, float a1, float4* b) {
  const float f0 = a0 * 4.f, f1 = a1 * 4.f;
  const float k0f = fminf(fmaxf(floorf(f0), 0.f), 3.f);
  const float k1f = fminf(fmaxf(floorf(f1), 0.f), 3.f);
  const float t0 = f0 - k0f, t1 = f1 - k1f;
  b->x = (1.f - t0) * (1.f - t1);   // (k0,   k1)
  b->y = (1.f - t0) * t1;           // (k0,   k1+1)
  b->z = t0 * (1.f - t1);           // (k0+1, k1)
  b->w = t0 * t1;                   // (k0+1, k1+1)
  return (int)k0f + 4 * (int)k1f;
}

__global__ __launch_bounds__(256) void cellcount_kernel(const int* __restrict__ ei,
                                                        const float* __restrict__ ea,
                                                        int* __restrict__ cnt) {
  const int e = blockIdx.x * 256 + threadIdx.x;
  if (e >= EDGES) return;
  const int d = ei[EDGES + e];
  float4 b;
  const int cell = cell_of(ea[2 * e], ea[2 * e + 1], &b);
  atomicAdd(&cnt[d * 16 + cell], 1);
}

__global__ __launch_bounds__(256) void nodesum_kernel(const int* __restrict__ cnt,
                                                      int* __restrict__ degi) {
  const int d = blockIdx.x * 256 + threadIdx.x;
  if (d >= NNODE) return;
  int s = 0;
  #pragma unroll
  for (int c = 0; c < 16; ++c) s += cnt[d * 16 + c];
  degi[d] = s;
}

__global__ __launch_bounds__(1024) void scan_kernel(const int* __restrict__ degi,
                                                    int* __restrict__ rp,
                                                    float* __restrict__ deg_inv) {
  __shared__ int sh[1024];
  const int tid = threadIdx.x;
  const int base = tid * 16;
  int loc[16];
  int sum = 0;
  #pragma unroll
  for (int i = 0; i < 16; ++i) { loc[i] = degi[base + i]; sum += loc[i]; }
  sh[tid] = sum;
  __syncthreads();
  for (int off = 1; off < 1024; off <<= 1) {
    int v = 0;
    if (tid >= off) v = sh[tid - off];
    __syncthreads();
    if (tid >= off) sh[tid] += v;
    __syncthreads();
  }
  int ex = sh[tid] - sum;
  #pragma unroll
  for (int i = 0; i < 16; ++i) {
    rp[base + i] = ex;
    ex += loc[i];
    deg_inv[base + i] = 1.f / (float)max(loc[i], 1);
  }
  if (tid == 1023) rp[NNODE] = ex;
}

__global__ __launch_bounds__(256) void rp2_kernel(const int* __restrict__ rp,
                                                  const int* __restrict__ cnt,
                                                  int* __restrict__ rp2) {
  const int d = blockIdx.x * 256 + threadIdx.x;
  if (d >= NNODE) return;
  int base = rp[d];
  #pragma unroll
  for (int c = 0; c < 16; ++c) {
    rp2[d * 16 + c] = base;
    base += cnt[d * 16 + c];
  }
  if (d == NNODE - 1) rp2[NNODE * 16] = base;
}

__global__ __launch_bounds__(256) void scatter2_kernel(const int* __restrict__ ei,
                                                       const float* __restrict__ ea,
                                                       const int* __restrict__ rp2,
                                                       int* __restrict__ cursor2,
                                                       int* __restrict__ esrc,
                                                       float4* __restrict__ ebasis) {
  const int e = blockIdx.x * 256 + threadIdx.x;
  if (e >= EDGES) return;
  const int s = ei[e];
  const int d = ei[EDGES + e];
  float4 b;
  const int cell = cell_of(ea[2 * e], ea[2 * e + 1], &b);
  const int pos = rp2[d * 16 + cell] + atomicAdd(&cursor2[d * 16 + cell], 1);
  esrc[pos] = s;
  ebasis[pos] = b;
}

// W (K x 64) + root appended -> fragment-contiguous layout:
// out[((ot*nkt + kt)<<9) + lif*8 + j], lif = (o&15) + ((k5>>3)<<4), j = k&7
__global__ __launch_bounds__(256) void wprep_frag(const float* __restrict__ W,
                                                  const float* __restrict__ root,
                                                  u16* __restrict__ out,
                                                  int kspfin, int nkt) {
  const int K = nkt * 32;
  const int i = blockIdx.x * 256 + threadIdx.x;
  if (i >= 64 * K) return;
  const int o = i / K, k = i % K;
  const float v = (k < kspfin) ? W[(size_t)k * 64 + o]
                               : root[(size_t)(k - kspfin) * 64 + o];
  const int ot = o >> 4, kt = k >> 5;
  const int lif = (o & 15) + (((k & 31) >> 3) << 4);
  out[(((size_t)(ot * nkt + kt)) << 9) + lif * 8 + (k & 7)] = f2b(v);
}

// edge-phase section macro (cell-sorted edges, compile-time tap slots)
#define SEC(K0, K1, BND)                                               \
  {                                                                    \
    const int eC = (BND);                                              \
    for (; e < eC; ++e) {                                              \
      const int sD = p.esrc[e + 3];                                    \
      const float4 b2 = p.ebasis[e + 2];                               \
      const float v2 = GATHER(sC);                                     \
      acc[(K0) + 5 * (K1)]     += b0.x * v0;                           \
      acc[(K0) + 5 * (K1) + 1] += b0.z * v0;                           \
      acc[(K0) + 5 * (K1) + 5] += b0.y * v0;                           \
      acc[(K0) + 5 * (K1) + 6] += b0.w * v0;                           \
      b0 = b1; b1 = b2; v0 = v1; v1 = v2; sC = sD;                     \
    }                                                                  \
  }

#define SEC_ALL                                                        \
  SEC(0, 0, q0.y) SEC(1, 0, q0.z) SEC(2, 0, q0.w) SEC(3, 0, q1.x)     \
  SEC(0, 1, q1.y) SEC(1, 1, q1.z) SEC(2, 1, q1.w) SEC(3, 1, q2.x)     \
  SEC(0, 2, q2.y) SEC(1, 2, q2.z) SEC(2, 2, q2.w) SEC(3, 2, q3.x)     \
  SEC(0, 3, q3.y) SEC(1, 3, q3.z) SEC(2, 3, q3.w) SEC(3, 3, eEnd)

#define SEC_PROLOGUE                                                   \
  const int4 q0 = *(const int4*)(p.rp2 + d * 16);                      \
  const int4 q1 = *(const int4*)(p.rp2 + d * 16 + 4);                  \
  const int4 q2 = *(const int4*)(p.rp2 + d * 16 + 8);                  \
  const int4 q3 = *(const int4*)(p.rp2 + d * 16 + 12);                 \
  const int eEnd = p.rp2[d * 16 + 16];                                 \
  int e = q0.x;                                                        \
  int sC;                                                              \
  float4 b0, b1;                                                       \
  float v0, v1;                                                        \
  {                                                                    \
    const int sA = p.esrc[e], sB = p.esrc[e + 1];                      \
    sC = p.esrc[e + 2];                                                \
    b0 = p.ebasis[e]; b1 = p.ebasis[e + 1];                            \
    v0 = GATHER(sA); v1 = GATHER(sB);                                  \
  }

// ---------------- edge kernels (no LDS, 1 node/wave, max TLP) ----------------

struct HEP {
  const u16* h_curb;
  const int* rp2;
  const int* esrc;
  const float4* ebasis;
  const float* deg_inv;
  u16* Uh;   // [1024 rt][52 kt][512 u16] fragment-contiguous
};

__global__ __launch_bounds__(256) void edge_h(HEP p) {
  const int wave = threadIdx.x >> 6, lane = threadIdx.x & 63;
  const int d = blockIdx.x * 4 + wave;
  float acc[25];
  #pragma unroll
  for (int k = 0; k < 25; ++k) acc[k] = 0.f;
  #define GATHER(S) b2f(p.h_curb[((S) << 6) + lane])
  SEC_PROLOGUE
  SEC_ALL
  #undef GATHER
  const float di = p.deg_inv[d];
  const int rt = d >> 4;
  const int lif8 = ((d & 15) + (((lane & 31) >> 3) << 4)) * 8 + (lane & 7);
  u16* ug = p.Uh + (((size_t)rt * NKT_H) << 9) + lif8;
  const int kth = lane >> 5;
  #pragma unroll
  for (int c = 0; c < 25; ++c)
    ug[(size_t)(2 * c + kth) << 9] = f2b(acc[c] * di);
  ug[(size_t)(50 + kth) << 9] = p.h_curb[(d << 6) + lane];
}

struct XEP {
  const u16* xTb;
  const int* rp2;
  const int* esrc;
  const float4* ebasis;
  const float* deg_inv;
  u16* Ux;   // chunk: [2048 rt][26 kt][512 u16]; rt = half*1024 + (n>>4)
};

__global__ __launch_bounds__(256) void edge_x(XEP p, int tp) {
  const int wave = threadIdx.x >> 6, lane = threadIdx.x & 63;
  const int half = lane >> 5, fl = lane & 31;
  const int d = blockIdx.x * 4 + wave;
  const u16* __restrict__ xb = p.xTb + (size_t)(tp * 2 + half) * NNODE * 32;
  float acc[25];
  #pragma unroll
  for (int k = 0; k < 25; ++k) acc[k] = 0.f;
  #define GATHER(S) b2f(xb[((S) << 5) + fl])
  SEC_PROLOGUE
  SEC_ALL
  #undef GATHER
  const float di = p.deg_inv[d];
  const int rt = (half << 10) + (d >> 4);
  const int lif8 = ((d & 15) + ((fl >> 3) << 4)) * 8 + (fl & 7);
  u16* ug = p.Ux + (((size_t)rt * NKT_X) << 9) + lif8;
  #pragma unroll
  for (int c = 0; c < 25; ++c)
    ug[(size_t)c << 9] = f2b(acc[c] * di);
  ug[(size_t)25 << 9] = xb[(d << 5) + fl];
}

// ---------------- gemm_x: U_x chunk @ Wx (W held in VGPRs) ----------------

struct XGP {
  const u16* Ux;
  const u16* Wxfrag;   // [3 gates][4 ot][26 kt][512]
  const float* b_xr; const float* b_xz; const float* b_xn;
  __half* xcr; __half* xcz; __half* xcn;
};

__global__ __launch_bounds__(768) void gemm_x(XGP p, int tp) {
  const int tid = threadIdx.x;
  const int wave = tid >> 6, lane = tid & 63;
  const int g = wave >> 2, ot = wave & 3;
  const int col = lane & 15, q = lane >> 4;
  const int o = ot * 16 + col;
  const float* bp = (g == 0) ? p.b_xr : (g == 1) ? p.b_xz : p.b_xn;
  __half* outp = (g == 0) ? p.xcr : (g == 1) ? p.xcz : p.xcn;
  const float bias = bp[o];
  // load this wave's full-K W tile into registers (26 x 16B/lane)
  bf16x8 w[NKT_X];
  const u16* wf = p.Wxfrag + (((size_t)(g * 4 + ot) * NKT_X) << 9) + lane * 8;
  #pragma unroll
  for (int kt = 0; kt < NKT_X; ++kt)
    w[kt] = *reinterpret_cast<const bf16x8*>(wf + ((size_t)kt << 9));

  for (int rl = 0; rl < 8; ++rl) {
    const int rt = blockIdx.x * 8 + rl;
    const u16* ua = p.Ux + (((size_t)rt * NKT_X) << 9) + lane * 8;
    f32x4 acc = f32x4{bias, bias, bias, bias};
    #pragma unroll
    for (int kt = 0; kt < NKT_X; ++kt) {
      const bf16x8 a = *reinterpret_cast<const bf16x8*>(ua + ((size_t)kt << 9));
      acc = __builtin_amdgcn_mfma_f32_16x16x32_bf16(a, w[kt], acc, 0, 0, 0);
    }
    const int t = tp * 2 + (rt >> 10);
    const int nbase = (rt & 1023) << 4;
    #pragma unroll
    for (int j = 0; j < 4; ++j) {
      const int n = nbase + q * 4 + j;
      outp[((size_t)t * NNODE + n) * 64 + o] = __float2half(acc[j]);
    }
  }
}

// ---------------- gemm_h + GRU (sequential step) ----------------

struct HGP {
  const u16* Uh;
  const u16* Whfrag;   // [2 gates][4 ot][52 kt][512]
  const float* b_hr; const float* b_hz;
  const float* h_cur;
  float* h_next;
  u16* h_nextb;
  const __half* xcr; const __half* xcz; const __half* xcn;
  u16* hs;
};

__global__ __launch_bounds__(512) void gemm_h(HGP p, int t) {
  __shared__ __align__(16) float4 UA4[3328];   // 53248 B; gates overlay after MFMA
  const int tid = threadIdx.x;
  const int wave = tid >> 6, lane = tid & 63;
  const int rt = blockIdx.x;
  // stage A row-tile (fragment-contiguous -> linear coalesced copy)
  {
    const float4* src = (const float4*)(p.Uh + (((size_t)rt * NKT_H) << 9));
    for (int i = tid; i < 3328; i += 512) UA4[i] = src[i];
  }
  __syncthreads();

  const int g = wave & 1, ot = wave >> 1;
  const int col = lane & 15, q = lane >> 4;
  const int o = ot * 16 + col;
  const float bias = g ? p.b_hz[o] : p.b_hr[o];
  f32x4 acc = f32x4{bias, bias, bias, bias};
  const u16* ua = (const u16*)UA4 + lane * 8;
  const u16* wf = p.Whfrag + (((size_t)(g * 4 + ot) * NKT_H) << 9) + lane * 8;
  #pragma unroll 4
  for (int kt = 0; kt < NKT_H; ++kt) {
    const bf16x8 a = *reinterpret_cast<const bf16x8*>(ua + ((size_t)kt << 9));
    const bf16x8 w = *reinterpret_cast<const bf16x8*>(wf + ((size_t)kt << 9));
    acc = __builtin_amdgcn_mfma_f32_16x16x32_bf16(a, w, acc, 0, 0, 0);
  }
  __syncthreads();
  float* gates = (float*)UA4;   // [2][16][64] overlay
  #pragma unroll
  for (int j = 0; j < 4; ++j)
    gates[(g << 10) + (q * 4 + j) * 64 + o] = acc[j];
  __syncthreads();

  // fused GRU: 1024 elems over 512 threads
  #pragma unroll
  for (int rep = 0; rep < 2; ++rep) {
    const int i = tid + rep * 512;
    const int nloc = i >> 6, oo = i & 63;
    const int node = (rt << 4) + nloc;
    const size_t idx = (size_t)node * 64 + oo;
    const size_t tix = (size_t)t * NNODE * 64 + idx;
    const float hrv = gates[nloc * 64 + oo];
    const float hzv = gates[1024 + nloc * 64 + oo];
    const float xrv = __half2float(p.xcr[tix]);
    const float xzv = __half2float(p.xcz[tix]);
    const float xnv = __half2float(p.xcn[tix]);
    const float r = 1.f / (1.f + __expf(-(xrv + hrv)));
    const float z = 1.f / (1.f + __expf(-(xzv + hzv)));
    const float ng = 1.f - 2.f / (__expf(2.f * (xnv + r * hrv)) + 1.f);  // tanh
    const float hp = p.h_cur[idx];
    const float hn = (1.f - z) * ng + z * hp;
    p.h_next[idx] = hn;
    const u16 hb = f2b(hn);
    p.h_nextb[idx] = hb;
    p.hs[tix] = hb;
  }
}

// ---------------- finalize: hs [t][n][o] bf16 -> out (B,G,H,T) f32 ----------------

__global__ __launch_bounds__(256) void finalize_kernel(const u16* __restrict__ hs,
                                                       float* __restrict__ out,
                                                       float* __restrict__ out_last) {
  const int i = blockIdx.x * 256 + threadIdx.x;   // i = n*64 + o
  if (i >= NNODE * 64) return;
  float* ob = out + (size_t)(i >> 6) * 640 + (size_t)(i & 63) * 10;
  #pragma unroll
  for (int t = 0; t < TSTEPS; ++t)
    ob[t] = b2f(hs[(size_t)t * NNODE * 64 + i]);
  out_last[i] = b2f(hs[(size_t)9 * NNODE * 64 + i]);
}

// ---------------- host launch ----------------

extern "C" void kernel_launch(void* const* d_in, const int* in_sizes, int n_in,
                              void* d_out, int out_size, void* d_ws, size_t ws_size,
                              hipStream_t stream) {
  const float* x = (const float*)d_in[0];
  const int* ei = (const int*)d_in[1];
  const float* ea = (const float*)d_in[2];
  const float* W_xr = (const float*)d_in[3];
  const float* root_xr = (const float*)d_in[4];
  const float* b_xr = (const float*)d_in[5];
  const float* W_hr = (const float*)d_in[6];
  const float* root_hr = (const float*)d_in[7];
  const float* b_hr = (const float*)d_in[8];
  const float* W_xz = (const float*)d_in[9];
  const float* root_xz = (const float*)d_in[10];
  const float* b_xz = (const float*)d_in[11];
  const float* W_hz = (const float*)d_in[12];
  const float* root_hz = (const float*)d_in[13];
  const float* b_hz = (const float*)d_in[14];
  const float* W_xn = (const float*)d_in[15];
  const float* root_xn = (const float*)d_in[16];
  const float* b_xn = (const float*)d_in[17];

  char* w = (char*)d_ws;
  u16* xTb = (u16*)w;          w += (size_t)TSTEPS * NNODE * 32 * 2;     // 10.5 MB
  __half* xcr = (__half*)w;    w += (size_t)TSTEPS * NNODE * 64 * 2;     // 21 MB
  __half* xcz = (__half*)w;    w += (size_t)TSTEPS * NNODE * 64 * 2;     // 21 MB
  __half* xcn = (__half*)w;    w += (size_t)TSTEPS * NNODE * 64 * 2;     // 21 MB
  u16* hs = (u16*)w;           w += (size_t)TSTEPS * NNODE * 64 * 2;     // 21 MB
  float* h0 = (float*)w;       w += (size_t)NNODE * HOUT * 4;
  float* h1 = (float*)w;       w += (size_t)NNODE * HOUT * 4;
  u16* h0b = (u16*)w;          w += (size_t)NNODE * HOUT * 2;
  u16* h1b = (u16*)w;          w += (size_t)NNODE * HOUT * 2;
  float4* ebasis = (float4*)w; w += (size_t)(EDGES + 16) * 16;
  int* esrc = (int*)w;         w += (size_t)(EDGES + 16) * 4;
  u16* Whfrag = (u16*)w;       w += (size_t)2 * 4 * NKT_H * 512 * 2;     // 416 KB
  u16* Wxfrag = (u16*)w;       w += (size_t)3 * 4 * NKT_X * 512 * 2;     // 312 KB
  u16* Uh = (u16*)w;           w += (size_t)1024 * NKT_H * 512 * 2;      // 54.5 MB
  u16* Ux = (u16*)w;           w += (size_t)2048 * NKT_X * 512 * 2;      // 54.5 MB
  int* cnt = (int*)w;          w += (size_t)NNODE * 16 * 4;              // 1 MB
  int* cursor2 = (int*)w;      w += (size_t)NNODE * 16 * 4;              // 1 MB
  int* rp2 = (int*)w;          w += (size_t)(NNODE * 16 + 16) * 4;       // 1 MB
  int* degi = (int*)w;         w += (size_t)NNODE * 4;
  int* rp = (int*)w;           w += (size_t)(NNODE + 4) * 4;
  float* deg_inv = (float*)w;  w += (size_t)NNODE * 4;

  hipMemsetAsync(cnt, 0, (size_t)NNODE * 16 * 4, stream);
  hipMemsetAsync(cursor2, 0, (size_t)NNODE * 16 * 4, stream);
  hipMemsetAsync(h0, 0, (size_t)NNODE * HOUT * 4, stream);
  hipMemsetAsync(h0b, 0, (size_t)NNODE * HOUT * 2, stream);
  hipMemsetAsync((void*)(ebasis + EDGES), 0, 16 * 16, stream);
  hipMemsetAsync(esrc + EDGES, 0, 16 * 4, stream);

  xpose_kernel<<<(NNODE * 32 + 255) / 256, 256, 0, stream>>>(x, xTb);
  cellcount_kernel<<<(EDGES + 255) / 256, 256, 0, stream>>>(ei, ea, cnt);
  nodesum_kernel<<<(NNODE + 255) / 256, 256, 0, stream>>>(cnt, degi);
  scan_kernel<<<1, 1024, 0, stream>>>(degi, rp, deg_inv);
  rp2_kernel<<<(NNODE + 255) / 256, 256, 0, stream>>>(rp, cnt, rp2);
  scatter2_kernel<<<(EDGES + 255) / 256, 256, 0, stream>>>(ei, ea, rp2, cursor2,
                                                           esrc, ebasis);
  const int gWH = (64 * NKT_H * 32 + 255) / 256;
  const int gWX = (64 * NKT_X * 32 + 255) / 256;
  wprep_frag<<<gWH, 256, 0, stream>>>(W_hr, root_hr, Whfrag, 1600, NKT_H);
  wprep_frag<<<gWH, 256, 0, stream>>>(W_hz, root_hz, Whfrag + (size_t)4 * NKT_H * 512, 1600, NKT_H);
  wprep_frag<<<gWX, 256, 0, stream>>>(W_xr, root_xr, Wxfrag, 800, NKT_X);
  wprep_frag<<<gWX, 256, 0, stream>>>(W_xz, root_xz, Wxfrag + (size_t)4 * NKT_X * 512, 800, NKT_X);
  wprep_frag<<<gWX, 256, 0, stream>>>(W_xn, root_xn, Wxfrag + (size_t)8 * NKT_X * 512, 800, NKT_X);

  // ---- x path: per t-pair, edge-accumulate then GEMM ----
  XEP xe;
  xe.xTb = xTb; xe.rp2 = rp2; xe.esrc = esrc; xe.ebasis = ebasis;
  xe.deg_inv = deg_inv; xe.Ux = Ux;
  XGP xg;
  xg.Ux = Ux; xg.Wxfrag = Wxfrag;
  xg.b_xr = b_xr; xg.b_xz = b_xz; xg.b_xn = b_xn;
  xg.xcr = xcr; xg.xcz = xcz; xg.xcn = xcn;
  for (int tp = 0; tp < TSTEPS / 2; ++tp) {
    edge_x<<<NNODE / 4, 256, 0, stream>>>(xe, tp);
    gemm_x<<<256, 768, 0, stream>>>(xg, tp);
  }

  // ---- h path: sequential steps ----
  HEP he;
  he.rp2 = rp2; he.esrc = esrc; he.ebasis = ebasis;
  he.deg_inv = deg_inv; he.Uh = Uh;
  HGP hg;
  hg.Uh = Uh; hg.Whfrag = Whfrag;
  hg.b_hr = b_hr; hg.b_hz = b_hz;
  hg.xcr = xcr; hg.xcz = xcz; hg.xcn = xcn;
  hg.hs = hs;

  float* ha = h0; float* hb_ = h1;
  u16* hab = h0b; u16* hbb = h1b;
  for (int t = 0; t < TSTEPS; ++t) {
    he.h_curb = hab;
    edge_h<<<NNODE / 4, 256, 0, stream>>>(he);
    hg.h_cur = ha; hg.h_next = hb_; hg.h_nextb = hbb;
    gemm_h<<<NNODE / 16, 512, 0, stream>>>(hg, t);
    float* tf = ha; ha = hb_; hb_ = tf;
    u16* tb = hab; hab = hbb; hbb = tb;
  }

  float* out = (float*)d_out;
  float* out_last = out + (size_t)NNODE * HOUT * TSTEPS;
  finalize_kernel<<<(NNODE * 64 + 255) / 256, 256, 0, stream>>>(hs, out, out_last);
}